// Round 1
// baseline (203.705 us; speedup 1.0000x reference)
//
#include <hip/hip_runtime.h>
#include <hip/hip_bf16.h>

typedef short short8 __attribute__((ext_vector_type(8)));
typedef float float4_ __attribute__((ext_vector_type(4)));
typedef unsigned short ushort_t;

// ---------------- constants ----------------
// params layout: theta[0:48], beta[48:58], c_r[58:67], c_o[67:69], c_s[69]
// outputs: J2d (32*128*21*2 = 172032), theta (196608), beta (40960)
#define OUT_THETA 172032
#define OUT_BETA  368640
#define NROW 4096
#define KDIM 5376
#define NPAD 80

// ws offsets (bytes)
#define WFRAG_OFF 0                 // 5376*80*2 = 860160
#define PART_OFF  860160            // 4*4096*80*4 = 5242880
#define JSD_OFF   6103040           // 480*4
#define JT_OFF    6104960           // 48*4
#define PSEL_OFF  6105152           // 2025*4
#define SSEL_OFF  6113252           // 150*4
#define TSEL_OFF  6113852           // 15*4
#define WSEL_OFF  6113912           // 80*4

__device__ __constant__ int c_jslot[16] = {0,5,6,7,9,10,11,17,18,19,13,14,15,1,2,3};
__device__ __constant__ int c_vslot[5]  = {4,8,12,16,20};

__device__ inline short f2bf(float f) {
  union { float f; unsigned u; } v; v.f = f;
  unsigned r = v.u + 0x7fffu + ((v.u >> 16) & 1u);
  return (short)(r >> 16);
}

__device__ inline short8 cvt8(float4_ a, float4_ b) {
  short8 r;
  r[0]=f2bf(a[0]); r[1]=f2bf(a[1]); r[2]=f2bf(a[2]); r[3]=f2bf(a[3]);
  r[4]=f2bf(b[0]); r[5]=f2bf(b[1]); r[6]=f2bf(b[2]); r[7]=f2bf(b[3]);
  return r;
}

// ---------------- setup: W->bf16 frag layout, J regressor folding, vertex gather ----------------
__global__ __launch_bounds__(256) void setup_kernel(
    const float* __restrict__ W, const float* __restrict__ shapedirs,
    const float* __restrict__ posedirs, const float* __restrict__ Jreg,
    const float* __restrict__ tmpl, const float* __restrict__ lbs,
    ushort_t* __restrict__ wfrag, float* __restrict__ jsd, float* __restrict__ jt,
    float* __restrict__ psel, float* __restrict__ ssel, float* __restrict__ tsel,
    float* __restrict__ wsel)
{
  int b = blockIdx.x, t = threadIdx.x;
  if (b < 1680) {
    // wfrag[(k>>3)*80 + n]*8 + (k&7)] = bf16(W[n][k])  (n>=70 -> 0)
    int idx = b*256 + t;              // 0..430079 = 80*5376
    int n = idx / KDIM, k = idx % KDIM;
    float v = (n < 70) ? W[(size_t)n*KDIM + k] : 0.f;
    wfrag[((size_t)(k>>3)*NPAD + n)*8 + (k&7)] = (ushort_t)f2bf(v);
  } else if (b < 1812) {
    // jsd[j][c][k] = sum_v Jreg[j][v]*shapedirs[v][c][k];  jt[j][c] = sum_v Jreg[j][v]*tmpl[v][c]
    int wv = (b-1680)*4 + (t>>6);     // 0..527
    int l = t & 63;
    float p = 0.f;
    if (wv < 480) {
      int j = wv/30, r = wv%30, c = r/10, kk = r%10;
      for (int v = l; v < 778; v += 64) p += Jreg[j*778+v]*shapedirs[(v*3+c)*10+kk];
    } else {
      int o = wv-480; int j = o/3, c = o%3;
      for (int v = l; v < 778; v += 64) p += Jreg[j*778+v]*tmpl[v*3+c];
    }
    for (int off = 32; off > 0; off >>= 1) p += __shfl_down(p, off);
    if (l == 0) { if (wv < 480) jsd[wv] = p; else jt[wv-480] = p; }
  } else {
    const int vtx[5] = {743,333,443,555,678};
    for (int s = t; s < 2270; s += 256) {
      if (s < 2025) { int vi = s/405, r = s%405, c = r/135, kk = r%135;
        psel[s] = posedirs[((size_t)vtx[vi]*3 + c)*135 + kk]; }
      else if (s < 2175) { int u = s-2025; int vi = u/30, r = u%30, c = r/10, kk = r%10;
        ssel[u] = shapedirs[((size_t)vtx[vi]*3 + c)*10 + kk]; }
      else if (s < 2190) { int u = s-2175; int vi = u/3, c = u%3;
        tsel[u] = tmpl[vtx[vi]*3 + c]; }
      else if (s < 2270) { int u = s-2190; int vi = u/16, j = u%16;
        wsel[u] = lbs[vtx[vi]*16 + j]; }
    }
  }
}

// ---------------- GEMM: params_part[kq][row][80] = x[rows][kq-range] @ W^T ----------------
// wave = 16 rows x 16 cols x 1344 K.  5 ntiles * 256 rowtiles * 4 ksplits = 5120 waves = 1280 blocks
__global__ __launch_bounds__(256) void gemm_params(
    const float* __restrict__ x, const ushort_t* __restrict__ wfrag,
    float* __restrict__ part)
{
  const int KQ = 1344, NCH = KQ/32;   // 42 chunks
  int gw = (blockIdx.x << 2) + (threadIdx.x >> 6);
  int l = threadIdx.x & 63;
  int nt = gw % 5;
  int rg = (gw / 5) & 255;
  int kq = gw / (5*256);
  int m0 = rg << 4, n0 = nt << 4, k0 = kq * KQ;
  int q = l >> 4, lm = l & 15;

  const float* ap = x + (size_t)(m0 + lm)*KDIM + k0 + q*8;
  const ushort_t* bp = wfrag + ((size_t)((k0>>3) + q)*NPAD + n0 + lm)*8;
  float4_ acc = {0.f,0.f,0.f,0.f};
  #pragma unroll 2
  for (int c = 0; c < NCH; ++c) {
    float4_ a0 = *(const float4_*)ap;
    float4_ a1 = *(const float4_*)(ap+4);
    short8 bfr = *(const short8*)bp;
    short8 afr = cvt8(a0, a1);
    acc = __builtin_amdgcn_mfma_f32_16x16x32_bf16(afr, bfr, acc, 0, 0, 0);
    ap += 32; bp += 4*NPAD*8;
  }
  // C layout: row=(lane>>4)*4+r, col=lane&15
  float* op = part + ((size_t)(kq*NROW) + m0)*NPAD + n0 + lm;
  #pragma unroll
  for (int r = 0; r < 4; ++r) op[(size_t)(q*4 + r)*NPAD] = acc[r];
}

// ---------------- decode: one wave per (b,t) item ----------------
__global__ __launch_bounds__(64) void decode_kernel(
    const float* __restrict__ part, const float* __restrict__ bvec,
    const float* __restrict__ comps, const float* __restrict__ meanh,
    const float* __restrict__ jsd, const float* __restrict__ jt,
    const float* __restrict__ psel, const float* __restrict__ ssel,
    const float* __restrict__ tsel, const float* __restrict__ wsel,
    float* __restrict__ out)
{
  int row = blockIdx.x;
  int l = threadIdx.x;
  __shared__ float P[70];
  __shared__ float HP[48];
  __shared__ float R[16][9];
  __shared__ float Jl[48];
  __shared__ float RES[16][16];
  __shared__ float Al[16][16];
  __shared__ float CH[5][4];
  __shared__ float M3[21][3];

  // stage A: reduce split-K partials + bias; emit theta/beta
  {
    float v = part[(size_t)row*NPAD + l]
            + part[(size_t)(NROW+row)*NPAD + l]
            + part[(size_t)(2*NROW+row)*NPAD + l]
            + part[(size_t)(3*NROW+row)*NPAD + l] + bvec[l];
    P[l] = v;
    if (l < 48) out[OUT_THETA + (size_t)row*48 + l] = v;
    else if (l < 58) out[OUT_BETA + (size_t)row*10 + (l-48)] = v;
    if (l < 6) {
      int c2 = l + 64;
      P[c2] = part[(size_t)row*NPAD + c2]
            + part[(size_t)(NROW+row)*NPAD + c2]
            + part[(size_t)(2*NROW+row)*NPAD + c2]
            + part[(size_t)(3*NROW+row)*NPAD + c2] + bvec[c2];
    }
  }
  __syncthreads();

  // stage B: hand_posed = [theta[:3], theta[3:48] @ comps + mean]
  if (l < 45) {
    float s = meanh[l];
    for (int k = 0; k < 45; ++k) s += P[3+k]*comps[k*45 + l];
    HP[3+l] = s;
  } else if (l < 48) HP[l-45] = P[l-45];
  __syncthreads();

  // stage C: rodrigues for 16 joints; stage D: J = jt + jsd . beta
  if (l < 16) {
    float rx = HP[3*l], ry = HP[3*l+1], rz = HP[3*l+2];
    float th = sqrtf(rx*rx + ry*ry + rz*rz + 1e-8f);
    float inv = 1.0f/th;
    float nx = rx*inv, ny = ry*inv, nz = rz*inv;
    float cth = cosf(th), sth = sinf(th), mc = 1.0f - cth;
    R[l][0] = cth + mc*nx*nx;     R[l][1] = mc*nx*ny - sth*nz;  R[l][2] = mc*nx*nz + sth*ny;
    R[l][3] = mc*ny*nx + sth*nz;  R[l][4] = cth + mc*ny*ny;     R[l][5] = mc*ny*nz - sth*nx;
    R[l][6] = mc*nz*nx - sth*ny;  R[l][7] = mc*nz*ny + sth*nx;  R[l][8] = cth + mc*nz*nz;
  }
  if (l < 48) {
    float s = jt[l];
    #pragma unroll
    for (int k = 0; k < 10; ++k) s += jsd[l*10+k]*P[48+k];
    Jl[l] = s;
  }
  __syncthreads();

  // stage E: kinematic chain
  if (l < 16) {
    int r = l >> 2, c = l & 3;
    RES[0][l] = (r < 3) ? ((c < 3) ? R[0][3*r+c] : Jl[r]) : ((c == 3) ? 1.f : 0.f);
  }
  __syncthreads();
  constexpr int PARS[15] = {0,1,2,0,4,5,0,7,8,0,10,11,0,13,14};
  #pragma unroll
  for (int i = 0; i < 15; ++i) {
    const int p = PARS[i];
    if (l < 16) {
      int r = l >> 2, c = l & 3;
      float s = (c == 3) ? RES[p][4*r+3] : 0.f;
      #pragma unroll
      for (int k = 0; k < 3; ++k) {
        float opv = (c < 3) ? R[i+1][3*k+c] : (Jl[3*(i+1)+k] - Jl[3*p+k]);
        s += RES[p][4*r+k]*opv;
      }
      RES[i+1][l] = s;
    }
    __syncthreads();
  }

  // stage F: A = results with col3 -= results[:, :3] . J   (all 64 lanes: j=l>>2, r=l&3)
  {
    int j = l >> 2, r = l & 3;
    float corr = RES[j][4*r]*Jl[3*j] + RES[j][4*r+1]*Jl[3*j+1] + RES[j][4*r+2]*Jl[3*j+2];
    Al[j][4*r+0] = RES[j][4*r+0];
    Al[j][4*r+1] = RES[j][4*r+1];
    Al[j][4*r+2] = RES[j][4*r+2];
    Al[j][4*r+3] = RES[j][4*r+3] - corr;
  }
  // stage G: curr_hand at the 5 selected vertices (lanes 0..14)
  if (l < 15) {
    int vi = l/3, ci = l%3;
    float s = tsel[l];
    #pragma unroll
    for (int k = 0; k < 10; ++k) s += ssel[l*10+k]*P[48+k];
    for (int j15 = 0; j15 < 15; ++j15) {
      #pragma unroll
      for (int e = 0; e < 9; ++e) s += psel[l*135 + j15*9 + e]*R[j15+1][e];
    }
    CH[vi][ci] = s;
  }
  __syncthreads();

  // stage H: assemble J3d_re = joints (from results[...,:3,3]) + 5 skinned vertices
  if (l < 48) {
    int j = l/3, c = l%3;
    M3[c_jslot[j]][c] = RES[j][4*c+3];
  } else if (l < 63) {
    int s0 = l - 48; int vi = s0/3, r = s0%3;
    float m = 0.f;
    #pragma unroll
    for (int j = 0; j < 16; ++j) {
      float tv = Al[j][4*r]*CH[vi][0] + Al[j][4*r+1]*CH[vi][1]
               + Al[j][4*r+2]*CH[vi][2] + Al[j][4*r+3];
      m += wsel[vi*16+j]*tv;
    }
    M3[c_vslot[vi]][r] = m;
  }
  __syncthreads();

  // stage I: J2d = c_s * (J3d_re @ c_r3)[:, :2] + c_o
  if (l < 42) {
    int k = l >> 1, d = l & 1;
    float s = M3[k][0]*P[58 + d] + M3[k][1]*P[58 + 3 + d] + M3[k][2]*P[58 + 6 + d];
    out[((size_t)row*21 + k)*2 + d] = P[69]*s + P[67+d];
  }
}

extern "C" void kernel_launch(void* const* d_in, const int* in_sizes, int n_in,
                              void* d_out, int out_size, void* d_ws, size_t ws_size,
                              hipStream_t stream) {
  const float* x         = (const float*)d_in[0];
  const float* W         = (const float*)d_in[1];
  const float* bvec      = (const float*)d_in[2];
  const float* comps     = (const float*)d_in[3];
  const float* meanh     = (const float*)d_in[4];
  const float* tmpl      = (const float*)d_in[5];
  const float* shapedirs = (const float*)d_in[6];
  const float* posedirs  = (const float*)d_in[7];
  const float* Jreg      = (const float*)d_in[8];
  const float* lbs       = (const float*)d_in[9];

  char* ws = (char*)d_ws;
  ushort_t* wfrag = (ushort_t*)(ws + WFRAG_OFF);
  float* part = (float*)(ws + PART_OFF);
  float* jsd  = (float*)(ws + JSD_OFF);
  float* jt   = (float*)(ws + JT_OFF);
  float* psel = (float*)(ws + PSEL_OFF);
  float* ssel = (float*)(ws + SSEL_OFF);
  float* tsel = (float*)(ws + TSEL_OFF);
  float* wsel = (float*)(ws + WSEL_OFF);
  float* out  = (float*)d_out;

  hipLaunchKernelGGL(setup_kernel, dim3(1813), dim3(256), 0, stream,
                     W, shapedirs, posedirs, Jreg, tmpl, lbs,
                     wfrag, jsd, jt, psel, ssel, tsel, wsel);
  hipLaunchKernelGGL(gemm_params, dim3(1280), dim3(256), 0, stream, x, wfrag, part);
  hipLaunchKernelGGL(decode_kernel, dim3(4096), dim3(64), 0, stream,
                     part, bvec, comps, meanh, jsd, jt, psel, ssel, tsel, wsel, out);
}

// Round 2
// 182.693 us; speedup vs baseline: 1.1150x; 1.1150x over previous
//
#include <hip/hip_runtime.h>
#include <hip/hip_bf16.h>

typedef short short8 __attribute__((ext_vector_type(8)));
typedef float float4_ __attribute__((ext_vector_type(4)));
typedef unsigned short ushort_t;

// params layout: theta[0:48], beta[48:58], c_r[58:67], c_o[67:69], c_s[69]
// outputs: J2d (32*128*21*2 = 172032), theta (196608), beta (40960)
#define OUT_THETA 172032
#define OUT_BETA  368640
#define NROW 4096
#define KDIM 5376
#define NPAD 80

__device__ __constant__ int c_jslot[16] = {0,5,6,7,9,10,11,17,18,19,13,14,15,1,2,3};
__device__ __constant__ int c_vslot[5]  = {4,8,12,16,20};

__device__ inline short f2bf(float f) {
  union { float f; unsigned u; } v; v.f = f;
  unsigned r = v.u + 0x7fffu + ((v.u >> 16) & 1u);
  return (short)(r >> 16);
}

__device__ inline short8 cvt8(float4_ a, float4_ b) {
  short8 r;
  r[0]=f2bf(a[0]); r[1]=f2bf(a[1]); r[2]=f2bf(a[2]); r[3]=f2bf(a[3]);
  r[4]=f2bf(b[0]); r[5]=f2bf(b[1]); r[6]=f2bf(b[2]); r[7]=f2bf(b[3]);
  return r;
}

// ---------------- setup: W->bf16 frag layout (vectorized), J folding, vertex gather ----------------
// blocks 0..209   : wfrag repack, thread=(n,kgroup), coalesced W reads, short8 stores
// blocks 210..341 : jsd/jt wave reductions
// block  342      : 5-vertex gather tables
__global__ __launch_bounds__(256) void setup_kernel(
    const float* __restrict__ W, const float* __restrict__ shapedirs,
    const float* __restrict__ posedirs, const float* __restrict__ Jreg,
    const float* __restrict__ tmpl, const float* __restrict__ lbs,
    ushort_t* __restrict__ wfrag, float* __restrict__ jsd, float* __restrict__ jt,
    float* __restrict__ psel, float* __restrict__ ssel, float* __restrict__ tsel,
    float* __restrict__ wsel)
{
  int b = blockIdx.x, t = threadIdx.x;
  if (b < 210) {
    int idx = b*256 + t;              // 0..53759 = 80 n * 672 kgroups
    int n = idx / 672, kg = idx % 672;
    short8 o;
    if (n < 70) {
      const float* wp = W + (size_t)n*KDIM + kg*8;
      float4_ w0 = *(const float4_*)wp;
      float4_ w1 = *(const float4_*)(wp+4);
      o = cvt8(w0, w1);
    } else {
      o = (short8){0,0,0,0,0,0,0,0};
    }
    *(short8*)(wfrag + ((size_t)kg*NPAD + n)*8) = o;
  } else if (b < 342) {
    // jsd[j][c][k] = sum_v Jreg[j][v]*shapedirs[v][c][k];  jt[j][c] = sum_v Jreg[j][v]*tmpl[v][c]
    int wv = (b-210)*4 + (t>>6);      // 0..527
    int l = t & 63;
    float p = 0.f;
    if (wv < 480) {
      int j = wv/30, r = wv%30, c = r/10, kk = r%10;
      for (int v = l; v < 778; v += 64) p += Jreg[j*778+v]*shapedirs[(v*3+c)*10+kk];
    } else {
      int o = wv-480; int j = o/3, c = o%3;
      for (int v = l; v < 778; v += 64) p += Jreg[j*778+v]*tmpl[v*3+c];
    }
    for (int off = 32; off > 0; off >>= 1) p += __shfl_down(p, off);
    if (l == 0) { if (wv < 480) jsd[wv] = p; else jt[wv-480] = p; }
  } else {
    const int vtx[5] = {743,333,443,555,678};
    for (int s = t; s < 2270; s += 256) {
      if (s < 2025) { int vi = s/405, r = s%405, c = r/135, kk = r%135;
        psel[s] = posedirs[((size_t)vtx[vi]*3 + c)*135 + kk]; }
      else if (s < 2175) { int u = s-2025; int vi = u/30, r = u%30, c = r/10, kk = r%10;
        ssel[u] = shapedirs[((size_t)vtx[vi]*3 + c)*10 + kk]; }
      else if (s < 2190) { int u = s-2175; int vi = u/3, c = u%3;
        tsel[u] = tmpl[vtx[vi]*3 + c]; }
      else if (s < 2270) { int u = s-2190; int vi = u/16, j = u%16;
        wsel[u] = lbs[vtx[vi]*16 + j]; }
    }
  }
}

// ---------------- GEMM: part[kq][row][80] += x @ W^T, 5 n-tiles fused per wave ----------------
// wave = 16 rows x 80 cols x (nchunk*32) K.  waves = 256 rowtiles * KS ksplits
__global__ __launch_bounds__(256) void gemm_params(
    const float* __restrict__ x, const ushort_t* __restrict__ wfrag,
    float* __restrict__ part, int nchunk)
{
  int gw = (blockIdx.x << 2) + (threadIdx.x >> 6);
  int l = threadIdx.x & 63;
  int rg = gw & 255;
  int kq = gw >> 8;
  int m0 = rg << 4;
  int k0 = kq * (nchunk << 5);
  int q = l >> 4, lm = l & 15;

  const float* ap = x + (size_t)(m0 + lm)*KDIM + k0 + q*8;
  const ushort_t* bp = wfrag + ((size_t)((k0>>3) + q)*NPAD + lm)*8;

  float4_ acc0 = {0.f,0.f,0.f,0.f}, acc1 = acc0, acc2 = acc0, acc3 = acc0, acc4 = acc0;

  // prefetch chunk 0
  float4_ a0 = *(const float4_*)ap;
  float4_ a1 = *(const float4_*)(ap+4);
  short8 b0 = *(const short8*)(bp);
  short8 b1 = *(const short8*)(bp+128);
  short8 b2 = *(const short8*)(bp+256);
  short8 b3 = *(const short8*)(bp+384);
  short8 b4 = *(const short8*)(bp+512);
  ap += 32; bp += 4*NPAD*8;

  for (int c = 0; c < nchunk-1; ++c) {
    float4_ na0 = *(const float4_*)ap;
    float4_ na1 = *(const float4_*)(ap+4);
    short8 nb0 = *(const short8*)(bp);
    short8 nb1 = *(const short8*)(bp+128);
    short8 nb2 = *(const short8*)(bp+256);
    short8 nb3 = *(const short8*)(bp+384);
    short8 nb4 = *(const short8*)(bp+512);
    ap += 32; bp += 4*NPAD*8;
    short8 af = cvt8(a0, a1);
    acc0 = __builtin_amdgcn_mfma_f32_16x16x32_bf16(af, b0, acc0, 0, 0, 0);
    acc1 = __builtin_amdgcn_mfma_f32_16x16x32_bf16(af, b1, acc1, 0, 0, 0);
    acc2 = __builtin_amdgcn_mfma_f32_16x16x32_bf16(af, b2, acc2, 0, 0, 0);
    acc3 = __builtin_amdgcn_mfma_f32_16x16x32_bf16(af, b3, acc3, 0, 0, 0);
    acc4 = __builtin_amdgcn_mfma_f32_16x16x32_bf16(af, b4, acc4, 0, 0, 0);
    a0 = na0; a1 = na1; b0 = nb0; b1 = nb1; b2 = nb2; b3 = nb3; b4 = nb4;
  }
  {
    short8 af = cvt8(a0, a1);
    acc0 = __builtin_amdgcn_mfma_f32_16x16x32_bf16(af, b0, acc0, 0, 0, 0);
    acc1 = __builtin_amdgcn_mfma_f32_16x16x32_bf16(af, b1, acc1, 0, 0, 0);
    acc2 = __builtin_amdgcn_mfma_f32_16x16x32_bf16(af, b2, acc2, 0, 0, 0);
    acc3 = __builtin_amdgcn_mfma_f32_16x16x32_bf16(af, b3, acc3, 0, 0, 0);
    acc4 = __builtin_amdgcn_mfma_f32_16x16x32_bf16(af, b4, acc4, 0, 0, 0);
  }

  // C layout: row=(lane>>4)*4+r, col=lane&15
  float* op = part + ((size_t)kq*NROW + m0 + q*4)*NPAD + lm;
  #pragma unroll
  for (int r = 0; r < 4; ++r) {
    op[(size_t)r*NPAD +  0] = acc0[r];
    op[(size_t)r*NPAD + 16] = acc1[r];
    op[(size_t)r*NPAD + 32] = acc2[r];
    op[(size_t)r*NPAD + 48] = acc3[r];
    op[(size_t)r*NPAD + 64] = acc4[r];
  }
}

// ---------------- decode: one wave per (b,t) item ----------------
__global__ __launch_bounds__(64) void decode_kernel(
    const float* __restrict__ part, const float* __restrict__ bvec,
    const float* __restrict__ comps, const float* __restrict__ meanh,
    const float* __restrict__ jsd, const float* __restrict__ jt,
    const float* __restrict__ psel, const float* __restrict__ ssel,
    const float* __restrict__ tsel, const float* __restrict__ wsel,
    float* __restrict__ out, int KS)
{
  int row = blockIdx.x;
  int l = threadIdx.x;
  __shared__ float P[70];
  __shared__ float HP[48];
  __shared__ float R[16][9];
  __shared__ float Jl[48];
  __shared__ float RES[16][16];
  __shared__ float Al[16][16];
  __shared__ float CH[5][4];
  __shared__ float M3[21][3];

  // stage A: reduce split-K partials + bias; emit theta/beta
  {
    float v = bvec[l];
    for (int k = 0; k < KS; ++k) v += part[((size_t)k*NROW + row)*NPAD + l];
    P[l] = v;
    if (l < 48) out[OUT_THETA + (size_t)row*48 + l] = v;
    else if (l < 58) out[OUT_BETA + (size_t)row*10 + (l-48)] = v;
    if (l < 6) {
      int c2 = l + 64;
      float w = bvec[c2];
      for (int k = 0; k < KS; ++k) w += part[((size_t)k*NROW + row)*NPAD + c2];
      P[c2] = w;
    }
  }
  __syncthreads();

  // stage B: hand_posed = [theta[:3], theta[3:48] @ comps + mean]
  if (l < 45) {
    float s = meanh[l];
    for (int k = 0; k < 45; ++k) s += P[3+k]*comps[k*45 + l];
    HP[3+l] = s;
  } else if (l < 48) HP[l-45] = P[l-45];
  __syncthreads();

  // stage C: rodrigues for 16 joints; stage D: J = jt + jsd . beta
  if (l < 16) {
    float rx = HP[3*l], ry = HP[3*l+1], rz = HP[3*l+2];
    float th = sqrtf(rx*rx + ry*ry + rz*rz + 1e-8f);
    float inv = 1.0f/th;
    float nx = rx*inv, ny = ry*inv, nz = rz*inv;
    float cth = cosf(th), sth = sinf(th), mc = 1.0f - cth;
    R[l][0] = cth + mc*nx*nx;     R[l][1] = mc*nx*ny - sth*nz;  R[l][2] = mc*nx*nz + sth*ny;
    R[l][3] = mc*ny*nx + sth*nz;  R[l][4] = cth + mc*ny*ny;     R[l][5] = mc*ny*nz - sth*nx;
    R[l][6] = mc*nz*nx - sth*ny;  R[l][7] = mc*nz*ny + sth*nx;  R[l][8] = cth + mc*nz*nz;
  }
  if (l < 48) {
    float s = jt[l];
    #pragma unroll
    for (int k = 0; k < 10; ++k) s += jsd[l*10+k]*P[48+k];
    Jl[l] = s;
  }
  __syncthreads();

  // stage E: kinematic chain
  if (l < 16) {
    int r = l >> 2, c = l & 3;
    RES[0][l] = (r < 3) ? ((c < 3) ? R[0][3*r+c] : Jl[r]) : ((c == 3) ? 1.f : 0.f);
  }
  __syncthreads();
  constexpr int PARS[15] = {0,1,2,0,4,5,0,7,8,0,10,11,0,13,14};
  #pragma unroll
  for (int i = 0; i < 15; ++i) {
    const int p = PARS[i];
    if (l < 16) {
      int r = l >> 2, c = l & 3;
      float s = (c == 3) ? RES[p][4*r+3] : 0.f;
      #pragma unroll
      for (int k = 0; k < 3; ++k) {
        float opv = (c < 3) ? R[i+1][3*k+c] : (Jl[3*(i+1)+k] - Jl[3*p+k]);
        s += RES[p][4*r+k]*opv;
      }
      RES[i+1][l] = s;
    }
    __syncthreads();
  }

  // stage F: A = results with col3 -= results[:, :3] . J   (all 64 lanes: j=l>>2, r=l&3)
  {
    int j = l >> 2, r = l & 3;
    float corr = RES[j][4*r]*Jl[3*j] + RES[j][4*r+1]*Jl[3*j+1] + RES[j][4*r+2]*Jl[3*j+2];
    Al[j][4*r+0] = RES[j][4*r+0];
    Al[j][4*r+1] = RES[j][4*r+1];
    Al[j][4*r+2] = RES[j][4*r+2];
    Al[j][4*r+3] = RES[j][4*r+3] - corr;
  }
  // stage G: curr_hand at the 5 selected vertices (lanes 0..14)
  if (l < 15) {
    int vi = l/3, ci = l%3;
    float s = tsel[l];
    #pragma unroll
    for (int k = 0; k < 10; ++k) s += ssel[l*10+k]*P[48+k];
    for (int j15 = 0; j15 < 15; ++j15) {
      #pragma unroll
      for (int e = 0; e < 9; ++e) s += psel[l*135 + j15*9 + e]*R[j15+1][e];
    }
    CH[vi][ci] = s;
  }
  __syncthreads();

  // stage H: assemble J3d_re = joints (results[...,:3,3]) + 5 skinned vertices
  if (l < 48) {
    int j = l/3, c = l%3;
    M3[c_jslot[j]][c] = RES[j][4*c+3];
  } else if (l < 63) {
    int s0 = l - 48; int vi = s0/3, r = s0%3;
    float m = 0.f;
    #pragma unroll
    for (int j = 0; j < 16; ++j) {
      float tv = Al[j][4*r]*CH[vi][0] + Al[j][4*r+1]*CH[vi][1]
               + Al[j][4*r+2]*CH[vi][2] + Al[j][4*r+3];
      m += wsel[vi*16+j]*tv;
    }
    M3[c_vslot[vi]][r] = m;
  }
  __syncthreads();

  // stage I: J2d = c_s * (J3d_re @ c_r3)[:, :2] + c_o
  if (l < 42) {
    int k = l >> 1, d = l & 1;
    float s = M3[k][0]*P[58 + d] + M3[k][1]*P[58 + 3 + d] + M3[k][2]*P[58 + 6 + d];
    out[((size_t)row*21 + k)*2 + d] = P[69]*s + P[67+d];
  }
}

extern "C" void kernel_launch(void* const* d_in, const int* in_sizes, int n_in,
                              void* d_out, int out_size, void* d_ws, size_t ws_size,
                              hipStream_t stream) {
  const float* x         = (const float*)d_in[0];
  const float* W         = (const float*)d_in[1];
  const float* bvec      = (const float*)d_in[2];
  const float* comps     = (const float*)d_in[3];
  const float* meanh     = (const float*)d_in[4];
  const float* tmpl      = (const float*)d_in[5];
  const float* shapedirs = (const float*)d_in[6];
  const float* posedirs  = (const float*)d_in[7];
  const float* Jreg      = (const float*)d_in[8];
  const float* lbs       = (const float*)d_in[9];

  // ws layout: part (KS*4096*80*4) | wfrag 860160 | jsd 1920 | jt 192 |
  //            psel 8100 | ssel 600 | tsel 60 | wsel 320
  const size_t PART_ONE = (size_t)NROW*NPAD*4;     // 1310720 per ksplit
  const size_t TAIL = 860160 + 1920 + 192 + 8100 + 600 + 60 + 320; // 871352
  int KS = 4;
  if (ws_size >= 12*PART_ONE + TAIL) KS = 12;
  else if (ws_size >= 6*PART_ONE + TAIL) KS = 6;
  const int nchunk = 168 / KS;                     // chunks of K=32 per split

  char* ws = (char*)d_ws;
  float*    part  = (float*)ws;
  ushort_t* wfrag = (ushort_t*)(ws + KS*PART_ONE);
  char*     tb    = ws + KS*PART_ONE + 860160;
  float* jsd  = (float*)tb;
  float* jt   = (float*)(tb + 1920);
  float* psel = (float*)(tb + 1920 + 192);
  float* ssel = (float*)(tb + 1920 + 192 + 8100);
  float* tsel = (float*)(tb + 1920 + 192 + 8100 + 600);
  float* wsel = (float*)(tb + 1920 + 192 + 8100 + 600 + 60);
  float* out  = (float*)d_out;

  hipLaunchKernelGGL(setup_kernel, dim3(343), dim3(256), 0, stream,
                     W, shapedirs, posedirs, Jreg, tmpl, lbs,
                     wfrag, jsd, jt, psel, ssel, tsel, wsel);
  hipLaunchKernelGGL(gemm_params, dim3(64*KS), dim3(256), 0, stream,
                     x, wfrag, part, nchunk);
  hipLaunchKernelGGL(decode_kernel, dim3(4096), dim3(64), 0, stream,
                     part, bvec, comps, meanh, jsd, jt, psel, ssel, tsel, wsel, out, KS);
}

// Round 3
// 179.849 us; speedup vs baseline: 1.1326x; 1.0158x over previous
//
#include <hip/hip_runtime.h>
#include <hip/hip_bf16.h>

typedef short short8 __attribute__((ext_vector_type(8)));
typedef float float4_ __attribute__((ext_vector_type(4)));
typedef unsigned short ushort_t;

// params layout: theta[0:48], beta[48:58], c_r[58:67], c_o[67:69], c_s[69]
// outputs: J2d (32*128*21*2 = 172032), theta (196608), beta (40960)
#define OUT_THETA 172032
#define OUT_BETA  368640
#define NROW 4096
#define KDIM 5376
#define NPAD 80
#define KS 12
#define NCHUNK 14        // 168 chunks of K=32, split 12 ways

__device__ __constant__ int c_jslot[16] = {0,5,6,7,9,10,11,17,18,19,13,14,15,1,2,3};
__device__ __constant__ int c_vslot[5]  = {4,8,12,16,20};

__device__ inline short f2bf(float f) {
  union { float f; unsigned u; } v; v.f = f;
  unsigned r = v.u + 0x7fffu + ((v.u >> 16) & 1u);
  return (short)(r >> 16);
}

__device__ inline short8 cvt8(float4_ a, float4_ b) {
  short8 r;
  r[0]=f2bf(a[0]); r[1]=f2bf(a[1]); r[2]=f2bf(a[2]); r[3]=f2bf(a[3]);
  r[4]=f2bf(b[0]); r[5]=f2bf(b[1]); r[6]=f2bf(b[2]); r[7]=f2bf(b[3]);
  return r;
}

// ---------------- setup: W->bf16 frag layout (vectorized), J folding, vertex gather ----------------
__global__ __launch_bounds__(256) void setup_kernel(
    const float* __restrict__ W, const float* __restrict__ shapedirs,
    const float* __restrict__ posedirs, const float* __restrict__ Jreg,
    const float* __restrict__ tmpl, const float* __restrict__ lbs,
    ushort_t* __restrict__ wfrag, float* __restrict__ jsd, float* __restrict__ jt,
    float* __restrict__ psel, float* __restrict__ ssel, float* __restrict__ tsel,
    float* __restrict__ wsel)
{
  int b = blockIdx.x, t = threadIdx.x;
  if (b < 210) {
    int idx = b*256 + t;              // 0..53759 = 80 n * 672 kgroups
    int n = idx / 672, kg = idx % 672;
    short8 o;
    if (n < 70) {
      const float* wp = W + (size_t)n*KDIM + kg*8;
      float4_ w0 = *(const float4_*)wp;
      float4_ w1 = *(const float4_*)(wp+4);
      o = cvt8(w0, w1);
    } else {
      o = (short8){0,0,0,0,0,0,0,0};
    }
    *(short8*)(wfrag + ((size_t)kg*NPAD + n)*8) = o;
  } else if (b < 342) {
    // jsd[j][c][k] = sum_v Jreg[j][v]*shapedirs[v][c][k];  jt[j][c] = sum_v Jreg[j][v]*tmpl[v][c]
    int wv = (b-210)*4 + (t>>6);      // 0..527
    int l = t & 63;
    float p = 0.f;
    if (wv < 480) {
      int j = wv/30, r = wv%30, c = r/10, kk = r%10;
      for (int v = l; v < 778; v += 64) p += Jreg[j*778+v]*shapedirs[(v*3+c)*10+kk];
    } else {
      int o = wv-480; int j = o/3, c = o%3;
      for (int v = l; v < 778; v += 64) p += Jreg[j*778+v]*tmpl[v*3+c];
    }
    for (int off = 32; off > 0; off >>= 1) p += __shfl_down(p, off);
    if (l == 0) { if (wv < 480) jsd[wv] = p; else jt[wv-480] = p; }
  } else {
    const int vtx[5] = {743,333,443,555,678};
    for (int s = t; s < 2270; s += 256) {
      if (s < 2025) { int vi = s/405, r = s%405, c = r/135, kk = r%135;
        psel[s] = posedirs[((size_t)vtx[vi]*3 + c)*135 + kk]; }
      else if (s < 2175) { int u = s-2025; int vi = u/30, r = u%30, c = r/10, kk = r%10;
        ssel[u] = shapedirs[((size_t)vtx[vi]*3 + c)*10 + kk]; }
      else if (s < 2190) { int u = s-2175; int vi = u/3, c = u%3;
        tsel[u] = tmpl[vtx[vi]*3 + c]; }
      else if (s < 2270) { int u = s-2190; int vi = u/16, j = u%16;
        wsel[u] = lbs[vtx[vi]*16 + j]; }
    }
  }
}

// ---------------- GEMM: part[kq][row][80] = x @ W^T, 5 n-tiles fused per wave ----------------
// fully unrolled compile-time K loop, explicit 2-deep software pipeline.
// wave = 16 rows x 80 cols x 448 K.  waves = 256 rowtiles * 12 ksplits = 3072
__global__ __launch_bounds__(256) void gemm_params(
    const float* __restrict__ x, const ushort_t* __restrict__ wfrag,
    float* __restrict__ part)
{
  int gw = (blockIdx.x << 2) + (threadIdx.x >> 6);
  int l = threadIdx.x & 63;
  int rg = gw & 255;
  int kq = gw >> 8;
  int m0 = rg << 4;
  int k0 = kq * (NCHUNK*32);
  int q = l >> 4, lm = l & 15;

  const float* ap = x + (size_t)(m0 + lm)*KDIM + k0 + q*8;
  const ushort_t* bp = wfrag + ((size_t)((k0>>3) + q)*NPAD + lm)*8;

  float4_ acc0 = {0.f,0.f,0.f,0.f}, acc1 = acc0, acc2 = acc0, acc3 = acc0, acc4 = acc0;

  float4_ a0[2], a1[2];
  short8  bb[2][5];

  // prologue: chunks 0 and 1 in flight
  #pragma unroll
  for (int s = 0; s < 2; ++s) {
    a0[s] = *(const float4_*)(ap + s*32);
    a1[s] = *(const float4_*)(ap + s*32 + 4);
    #pragma unroll
    for (int n = 0; n < 5; ++n)
      bb[s][n] = *(const short8*)(bp + s*(4*NPAD*8) + n*128);
  }

  #pragma unroll
  for (int c = 0; c < NCHUNK; ++c) {
    const int s = c & 1;
    short8 af = cvt8(a0[s], a1[s]);
    acc0 = __builtin_amdgcn_mfma_f32_16x16x32_bf16(af, bb[s][0], acc0, 0, 0, 0);
    acc1 = __builtin_amdgcn_mfma_f32_16x16x32_bf16(af, bb[s][1], acc1, 0, 0, 0);
    acc2 = __builtin_amdgcn_mfma_f32_16x16x32_bf16(af, bb[s][2], acc2, 0, 0, 0);
    acc3 = __builtin_amdgcn_mfma_f32_16x16x32_bf16(af, bb[s][3], acc3, 0, 0, 0);
    acc4 = __builtin_amdgcn_mfma_f32_16x16x32_bf16(af, bb[s][4], acc4, 0, 0, 0);
    if (c + 2 < NCHUNK) {
      a0[s] = *(const float4_*)(ap + (c+2)*32);
      a1[s] = *(const float4_*)(ap + (c+2)*32 + 4);
      #pragma unroll
      for (int n = 0; n < 5; ++n)
        bb[s][n] = *(const short8*)(bp + (size_t)(c+2)*(4*NPAD*8) + n*128);
    }
  }

  // C layout: row=(lane>>4)*4+r, col=lane&15
  float* op = part + ((size_t)kq*NROW + m0 + q*4)*NPAD + lm;
  #pragma unroll
  for (int r = 0; r < 4; ++r) {
    op[(size_t)r*NPAD +  0] = acc0[r];
    op[(size_t)r*NPAD + 16] = acc1[r];
    op[(size_t)r*NPAD + 32] = acc2[r];
    op[(size_t)r*NPAD + 48] = acc3[r];
    op[(size_t)r*NPAD + 64] = acc4[r];
  }
}

// ---------------- decode: one wave per (b,t) item ----------------
__global__ __launch_bounds__(64) void decode_kernel(
    const float* __restrict__ part, const float* __restrict__ bvec,
    const float* __restrict__ comps, const float* __restrict__ meanh,
    const float* __restrict__ jsd, const float* __restrict__ jt,
    const float* __restrict__ psel, const float* __restrict__ ssel,
    const float* __restrict__ tsel, const float* __restrict__ wsel,
    float* __restrict__ out)
{
  int row = blockIdx.x;
  int l = threadIdx.x;
  __shared__ float P[70];
  __shared__ float HP[48];
  __shared__ float R[16][9];
  __shared__ float Jl[48];
  __shared__ float RES[16][16];
  __shared__ float Al[16][16];
  __shared__ float CH[5][4];
  __shared__ float M3[21][3];

  // stage A: reduce split-K partials + bias; emit theta/beta
  {
    float v = bvec[l];
    #pragma unroll
    for (int k = 0; k < KS; ++k) v += part[((size_t)k*NROW + row)*NPAD + l];
    P[l] = v;
    if (l < 48) out[OUT_THETA + (size_t)row*48 + l] = v;
    else if (l < 58) out[OUT_BETA + (size_t)row*10 + (l-48)] = v;
    if (l < 6) {
      int c2 = l + 64;
      float w = bvec[c2];
      #pragma unroll
      for (int k = 0; k < KS; ++k) w += part[((size_t)k*NROW + row)*NPAD + c2];
      P[c2] = w;
    }
  }
  __syncthreads();

  // stage B: hand_posed = [theta[:3], theta[3:48] @ comps + mean]
  if (l < 45) {
    float s = meanh[l];
    for (int k = 0; k < 45; ++k) s += P[3+k]*comps[k*45 + l];
    HP[3+l] = s;
  } else if (l < 48) HP[l-45] = P[l-45];
  __syncthreads();

  // stage C: rodrigues for 16 joints; stage D: J = jt + jsd . beta
  if (l < 16) {
    float rx = HP[3*l], ry = HP[3*l+1], rz = HP[3*l+2];
    float th = sqrtf(rx*rx + ry*ry + rz*rz + 1e-8f);
    float inv = 1.0f/th;
    float nx = rx*inv, ny = ry*inv, nz = rz*inv;
    float cth = cosf(th), sth = sinf(th), mc = 1.0f - cth;
    R[l][0] = cth + mc*nx*nx;     R[l][1] = mc*nx*ny - sth*nz;  R[l][2] = mc*nx*nz + sth*ny;
    R[l][3] = mc*ny*nx + sth*nz;  R[l][4] = cth + mc*ny*ny;     R[l][5] = mc*ny*nz - sth*nx;
    R[l][6] = mc*nz*nx - sth*ny;  R[l][7] = mc*nz*ny + sth*nx;  R[l][8] = cth + mc*nz*nz;
  }
  if (l < 48) {
    float s = jt[l];
    #pragma unroll
    for (int k = 0; k < 10; ++k) s += jsd[l*10+k]*P[48+k];
    Jl[l] = s;
  }
  __syncthreads();

  // stage E: kinematic chain
  if (l < 16) {
    int r = l >> 2, c = l & 3;
    RES[0][l] = (r < 3) ? ((c < 3) ? R[0][3*r+c] : Jl[r]) : ((c == 3) ? 1.f : 0.f);
  }
  __syncthreads();
  constexpr int PARS[15] = {0,1,2,0,4,5,0,7,8,0,10,11,0,13,14};
  #pragma unroll
  for (int i = 0; i < 15; ++i) {
    const int p = PARS[i];
    if (l < 16) {
      int r = l >> 2, c = l & 3;
      float s = (c == 3) ? RES[p][4*r+3] : 0.f;
      #pragma unroll
      for (int k = 0; k < 3; ++k) {
        float opv = (c < 3) ? R[i+1][3*k+c] : (Jl[3*(i+1)+k] - Jl[3*p+k]);
        s += RES[p][4*r+k]*opv;
      }
      RES[i+1][l] = s;
    }
    __syncthreads();
  }

  // stage F: A = results with col3 -= results[:, :3] . J   (all 64 lanes: j=l>>2, r=l&3)
  {
    int j = l >> 2, r = l & 3;
    float corr = RES[j][4*r]*Jl[3*j] + RES[j][4*r+1]*Jl[3*j+1] + RES[j][4*r+2]*Jl[3*j+2];
    Al[j][4*r+0] = RES[j][4*r+0];
    Al[j][4*r+1] = RES[j][4*r+1];
    Al[j][4*r+2] = RES[j][4*r+2];
    Al[j][4*r+3] = RES[j][4*r+3] - corr;
  }
  // stage G: curr_hand at the 5 selected vertices (lanes 0..14)
  if (l < 15) {
    int vi = l/3, ci = l%3;
    float s = tsel[l];
    #pragma unroll
    for (int k = 0; k < 10; ++k) s += ssel[l*10+k]*P[48+k];
    for (int j15 = 0; j15 < 15; ++j15) {
      #pragma unroll
      for (int e = 0; e < 9; ++e) s += psel[l*135 + j15*9 + e]*R[j15+1][e];
    }
    CH[vi][ci] = s;
  }
  __syncthreads();

  // stage H: assemble J3d_re = joints (results[...,:3,3]) + 5 skinned vertices
  if (l < 48) {
    int j = l/3, c = l%3;
    M3[c_jslot[j]][c] = RES[j][4*c+3];
  } else if (l < 63) {
    int s0 = l - 48; int vi = s0/3, r = s0%3;
    float m = 0.f;
    #pragma unroll
    for (int j = 0; j < 16; ++j) {
      float tv = Al[j][4*r]*CH[vi][0] + Al[j][4*r+1]*CH[vi][1]
               + Al[j][4*r+2]*CH[vi][2] + Al[j][4*r+3];
      m += wsel[vi*16+j]*tv;
    }
    M3[c_vslot[vi]][r] = m;
  }
  __syncthreads();

  // stage I: J2d = c_s * (J3d_re @ c_r3)[:, :2] + c_o
  if (l < 42) {
    int k = l >> 1, d = l & 1;
    float s = M3[k][0]*P[58 + d] + M3[k][1]*P[58 + 3 + d] + M3[k][2]*P[58 + 6 + d];
    out[((size_t)row*21 + k)*2 + d] = P[69]*s + P[67+d];
  }
}

extern "C" void kernel_launch(void* const* d_in, const int* in_sizes, int n_in,
                              void* d_out, int out_size, void* d_ws, size_t ws_size,
                              hipStream_t stream) {
  const float* x         = (const float*)d_in[0];
  const float* W         = (const float*)d_in[1];
  const float* bvec      = (const float*)d_in[2];
  const float* comps     = (const float*)d_in[3];
  const float* meanh     = (const float*)d_in[4];
  const float* tmpl      = (const float*)d_in[5];
  const float* shapedirs = (const float*)d_in[6];
  const float* posedirs  = (const float*)d_in[7];
  const float* Jreg      = (const float*)d_in[8];
  const float* lbs       = (const float*)d_in[9];

  // ws layout: part (12*4096*80*4 = 15.7 MB) | wfrag 860160 | jsd 1920 | jt 192 |
  //            psel 8100 | ssel 600 | tsel 60 | wsel 320
  const size_t PART_ONE = (size_t)NROW*NPAD*4;     // 1310720 per ksplit

  char* ws = (char*)d_ws;
  float*    part  = (float*)ws;
  ushort_t* wfrag = (ushort_t*)(ws + KS*PART_ONE);
  char*     tb    = ws + KS*PART_ONE + 860160;
  float* jsd  = (float*)tb;
  float* jt   = (float*)(tb + 1920);
  float* psel = (float*)(tb + 1920 + 192);
  float* ssel = (float*)(tb + 1920 + 192 + 8100);
  float* tsel = (float*)(tb + 1920 + 192 + 8100 + 600);
  float* wsel = (float*)(tb + 1920 + 192 + 8100 + 600 + 60);
  float* out  = (float*)d_out;

  hipLaunchKernelGGL(setup_kernel, dim3(343), dim3(256), 0, stream,
                     W, shapedirs, posedirs, Jreg, tmpl, lbs,
                     wfrag, jsd, jt, psel, ssel, tsel, wsel);
  hipLaunchKernelGGL(gemm_params, dim3(64*KS), dim3(256), 0, stream,
                     x, wfrag, part);
  hipLaunchKernelGGL(decode_kernel, dim3(4096), dim3(64), 0, stream,
                     part, bvec, comps, meanh, jsd, jt, psel, ssel, tsel, wsel, out);
}